// Round 1
// baseline (1138.162 us; speedup 1.0000x reference)
//
#include <hip/hip_runtime.h>
#include <hip/hip_bf16.h>
#include <stdint.h>

// ---------------------------------------------------------------------------
// Types
// ---------------------------------------------------------------------------
typedef __bf16 bf16x8 __attribute__((ext_vector_type(8)));
typedef float  f32x4  __attribute__((ext_vector_type(4)));

typedef __attribute__((address_space(1))) void gvoid;
typedef __attribute__((address_space(3))) void lvoid;

__device__ __forceinline__ void async16(void* lds, const void* g) {
    // global -> LDS direct copy, 16B per lane; LDS dest = wave-uniform base + lane*16
    __builtin_amdgcn_global_load_lds((gvoid*)g, (lvoid*)lds, 16, 0, 0);
}

// ---------------------------------------------------------------------------
// Elementwise f32 -> bf16 convert
// ---------------------------------------------------------------------------
__global__ void cvt_f32_to_bf16(const float* __restrict__ in,
                                __hip_bfloat16* __restrict__ out, long n) {
    long i = ((long)blockIdx.x * blockDim.x + threadIdx.x) * 4;
    if (i < n) {
        float4 v = *(const float4*)(in + i);
        __hip_bfloat162* d = (__hip_bfloat162*)(out + i);
        d[0] = __float22bfloat162_rn(make_float2(v.x, v.y));
        d[1] = __float22bfloat162_rn(make_float2(v.z, v.w));
    }
}

// ---------------------------------------------------------------------------
// Transpose f32 [R][C] -> bf16 [C][R]   (weights; R,C multiples of 32)
// ---------------------------------------------------------------------------
__global__ void transpose_f32_bf16(const float* __restrict__ in,
                                   __hip_bfloat16* __restrict__ out,
                                   int R, int C) {
    __shared__ float t[32][33];
    int c0 = blockIdx.x * 32, r0 = blockIdx.y * 32;
    int tx = threadIdx.x, ty = threadIdx.y;
#pragma unroll
    for (int i = 0; i < 4; ++i) {
        int r = r0 + ty + i * 8;
        t[ty + i * 8][tx] = in[(long)r * C + c0 + tx];
    }
    __syncthreads();
#pragma unroll
    for (int i = 0; i < 4; ++i) {
        int c = c0 + ty + i * 8;
        out[(long)c * R + r0 + tx] = __float2bfloat16(t[tx][ty + i * 8]);
    }
}

// ---------------------------------------------------------------------------
// V [8192][1024] bf16  ->  Vt [128(bh)][64(d)][1024(s)] bf16
// ---------------------------------------------------------------------------
__global__ void transpose_v(const __hip_bfloat16* __restrict__ V,
                            __hip_bfloat16* __restrict__ Vt) {
    __shared__ __hip_bfloat16 t[32][33];
    int s0 = blockIdx.x * 32, d0 = blockIdx.y * 32, z = blockIdx.z;
    int b = z >> 4, h = z & 15;
    int tx = threadIdx.x, ty = threadIdx.y;
#pragma unroll
    for (int i = 0; i < 4; ++i) {
        int s = s0 + ty + i * 8;
        t[ty + i * 8][tx] = V[((long)b * 1024 + s) * 1024 + h * 64 + d0 + tx];
    }
    __syncthreads();
#pragma unroll
    for (int i = 0; i < 4; ++i) {
        int d = d0 + ty + i * 8;
        Vt[((long)z * 64 + d) * 1024 + s0 + tx] = t[tx][ty + i * 8];
    }
}

// ---------------------------------------------------------------------------
// Batched GEMM:  C[z] = A[z] @ Bt[z]^T  (+ epilogue)
//   A: [M][K]  (bf16 row-major, or f32 if AF32 — converted during staging)
//   Bt: [N][K] bf16 row-major (i.e. B transposed)
//   z decomposed as (zb, zh) = (z / H, z % H), per-operand strides.
// Tile: BM x BN, 4 waves (2x2), BK=32, mfma_f32_16x16x32_bf16.
// Epilogue: v = acc*scale; mask? (mask[col]? v : -1e9); +bias; relu; +res;
//           store f32 and/or bf16.
// ---------------------------------------------------------------------------
template <int BM, int BN, bool AF32>
__global__ void __launch_bounds__(256)
gemm_bt(const void* __restrict__ Ap, long a_sb, long a_sh, int lda,
        const __hip_bfloat16* __restrict__ Bt, long b_sb, long b_sh, int ldb,
        int K, int H, float scale,
        const int* __restrict__ mask, int mask_ld,
        const float* __restrict__ bias,
        const float* __restrict__ res, long r_sb, long r_sh, int ldres,
        float* __restrict__ Cf, __hip_bfloat16* __restrict__ Cb,
        long c_sb, long c_sh, int ldc, int relu) {
    constexpr int FM = BM / 32, FN = BN / 32;
    __shared__ __align__(16) __hip_bfloat16 sA[BM * 32];
    __shared__ __align__(16) __hip_bfloat16 sB[BN * 32];

    const int tid = threadIdx.x;
    const int lane = tid & 63, wave = tid >> 6;
    const int wr = wave >> 1, wc = wave & 1;
    const int r16 = lane & 15, kg = lane >> 4;
    const long zb = blockIdx.z / H, zh = blockIdx.z % H;
    const long row0 = (long)blockIdx.x * BM;
    const long col0 = (long)blockIdx.y * BN;

    const float* Af = nullptr;
    const __hip_bfloat16* Ab = nullptr;
    if constexpr (AF32) Af = (const float*)Ap + zb * a_sb + zh * a_sh;
    else                Ab = (const __hip_bfloat16*)Ap + zb * a_sb + zh * a_sh;
    const __hip_bfloat16* Bb = Bt + zb * b_sb + zh * b_sh;

    f32x4 acc[FM][FN] = {};

    for (int kt = 0; kt < K; kt += 32) {
        // ---- stage A tile [BM][32] ----
        if constexpr (AF32) {
            for (int e = tid * 4; e < BM * 32; e += 1024) {
                int r = e >> 5, kk = e & 31;
                float4 v = *(const float4*)(Af + (row0 + r) * (long)lda + kt + kk);
                __hip_bfloat162* d = (__hip_bfloat162*)&sA[e];
                d[0] = __float22bfloat162_rn(make_float2(v.x, v.y));
                d[1] = __float22bfloat162_rn(make_float2(v.z, v.w));
            }
        } else {
            constexpr int CHA = BM / 16;  // 1KB chunks
            for (int c = wave; c < CHA; c += 4) {
                int e = c * 512 + lane * 8;
                int r = e >> 5, kk = e & 31;
                async16(&sA[c * 512], Ab + (row0 + r) * (long)lda + kt + kk);
            }
        }
        // ---- stage B tile [BN][32] ----
        {
            constexpr int CHB = BN / 16;
            for (int c = wave; c < CHB; c += 4) {
                int e = c * 512 + lane * 8;
                int r = e >> 5, kk = e & 31;
                async16(&sB[c * 512], Bb + (col0 + r) * (long)ldb + kt + kk);
            }
        }
        __syncthreads();

        bf16x8 av[FM], bv[FN];
#pragma unroll
        for (int m = 0; m < FM; ++m)
            av[m] = *(const bf16x8*)&sA[(wr * (BM / 2) + m * 16 + r16) * 32 + kg * 8];
#pragma unroll
        for (int n = 0; n < FN; ++n)
            bv[n] = *(const bf16x8*)&sB[(wc * (BN / 2) + n * 16 + r16) * 32 + kg * 8];
#pragma unroll
        for (int m = 0; m < FM; ++m)
#pragma unroll
            for (int n = 0; n < FN; ++n)
                acc[m][n] = __builtin_amdgcn_mfma_f32_16x16x32_bf16(av[m], bv[n], acc[m][n], 0, 0, 0);
        __syncthreads();
    }

    // ---- epilogue ----
    const float* resb = res ? res + zb * r_sb + zh * r_sh : nullptr;
    float* cfb = Cf ? Cf + zb * c_sb + zh * c_sh : nullptr;
    __hip_bfloat16* cbb = Cb ? Cb + zb * c_sb + zh * c_sh : nullptr;
    const int* mk = mask ? mask + zb * mask_ld : nullptr;

#pragma unroll
    for (int m = 0; m < FM; ++m) {
        const long rg0 = row0 + wr * (BM / 2) + m * 16 + kg * 4;
#pragma unroll
        for (int n = 0; n < FN; ++n) {
            const long cg = col0 + wc * (BN / 2) + n * 16 + r16;
#pragma unroll
            for (int i = 0; i < 4; ++i) {
                const long rg = rg0 + i;
                float v = acc[m][n][i] * scale;
                if (mk) v = mk[cg] ? v : -1e9f;
                if (bias) v += bias[cg];
                if (relu) v = fmaxf(v, 0.f);
                if (resb) v += resb[rg * (long)ldres + cg];
                const long off = rg * (long)ldc + cg;
                if (cfb) cfb[off] = v;
                if (cbb) cbb[off] = __float2bfloat16(v);
            }
        }
    }
}

// ---------------------------------------------------------------------------
// Row softmax in place; rows of 1024 f32; one wave per row.
// ---------------------------------------------------------------------------
__global__ void softmax_rows(float* __restrict__ data) {
    const long row = (long)blockIdx.x * 4 + (threadIdx.x >> 6);
    const int lane = threadIdx.x & 63;
    float4* p = (float4*)(data + row * 1024);
    float4 v[4];
#pragma unroll
    for (int j = 0; j < 4; ++j) v[j] = p[j * 64 + lane];

    float mx = -3.4e38f;
#pragma unroll
    for (int j = 0; j < 4; ++j)
        mx = fmaxf(mx, fmaxf(fmaxf(v[j].x, v[j].y), fmaxf(v[j].z, v[j].w)));
#pragma unroll
    for (int o = 32; o > 0; o >>= 1) mx = fmaxf(mx, __shfl_xor(mx, o));

    float s = 0.f;
#pragma unroll
    for (int j = 0; j < 4; ++j) {
        v[j].x = __expf(v[j].x - mx);
        v[j].y = __expf(v[j].y - mx);
        v[j].z = __expf(v[j].z - mx);
        v[j].w = __expf(v[j].w - mx);
        s += v[j].x + v[j].y + v[j].z + v[j].w;
    }
#pragma unroll
    for (int o = 32; o > 0; o >>= 1) s += __shfl_xor(s, o);

    const float inv = 1.f / s;
#pragma unroll
    for (int j = 0; j < 4; ++j) {
        v[j].x *= inv; v[j].y *= inv; v[j].z *= inv; v[j].w *= inv;
        p[j * 64 + lane] = v[j];
    }
}

// ---------------------------------------------------------------------------
// Launch
// ---------------------------------------------------------------------------
extern "C" void kernel_launch(void* const* d_in, const int* in_sizes, int n_in,
                              void* d_out, int out_size, void* d_ws, size_t ws_size,
                              hipStream_t stream) {
    const int B = 8, S = 1024, D = 1024, H = 16, DK = 64, DFF = 4096;
    const long SD = (long)B * S * D;  // 8M tokens*dim

    const float* X  = (const float*)d_in[0];
    const int*  msk = (const int*)d_in[1];
    const float* wq = (const float*)d_in[3];
    const float* wk = (const float*)d_in[4];
    const float* wv = (const float*)d_in[5];
    const float* wo = (const float*)d_in[6];
    const float* w1 = (const float*)d_in[7];
    const float* b1 = (const float*)d_in[8];
    const float* w2 = (const float*)d_in[9];
    const float* b2 = (const float*)d_in[10];

    float* out  = (float*)d_out;
    float* attn = out + SD;  // [8][16][1024][1024]

    char* ws = (char*)d_ws;
    auto alloc = [&](size_t bytes) {
        char* p = ws;
        ws += (bytes + 255) & ~(size_t)255;
        return p;
    };
    __hip_bfloat16* Xb   = (__hip_bfloat16*)alloc(SD * 2);
    __hip_bfloat16* Qb   = (__hip_bfloat16*)alloc(SD * 2);
    __hip_bfloat16* Kb   = (__hip_bfloat16*)alloc(SD * 2);
    __hip_bfloat16* Vb   = (__hip_bfloat16*)alloc(SD * 2);
    __hip_bfloat16* Vt   = (__hip_bfloat16*)alloc(SD * 2);
    __hip_bfloat16* Ctx  = (__hip_bfloat16*)alloc(SD * 2);
    __hip_bfloat16* EncB = (__hip_bfloat16*)alloc(SD * 2);
    __hip_bfloat16* Hb   = (__hip_bfloat16*)alloc((long)B * S * DFF * 2);
    float*          EncF = (float*)alloc(SD * 4);
    __hip_bfloat16* Wqt  = (__hip_bfloat16*)alloc((long)D * D * 2);
    __hip_bfloat16* Wkt  = (__hip_bfloat16*)alloc((long)D * D * 2);
    __hip_bfloat16* Wvt  = (__hip_bfloat16*)alloc((long)D * D * 2);
    __hip_bfloat16* Wot  = (__hip_bfloat16*)alloc((long)D * D * 2);
    __hip_bfloat16* W1t  = (__hip_bfloat16*)alloc((long)D * DFF * 2);
    __hip_bfloat16* W2t  = (__hip_bfloat16*)alloc((long)D * DFF * 2);
    (void)ws_size; (void)in_sizes; (void)n_in; (void)out_size;

    dim3 tb(32, 8);
    // prep
    cvt_f32_to_bf16<<<(int)(SD / 4 / 256), 256, 0, stream>>>(X, Xb, SD);
    transpose_f32_bf16<<<dim3(32, 32), tb, 0, stream>>>(wq, Wqt, D, D);
    transpose_f32_bf16<<<dim3(32, 32), tb, 0, stream>>>(wk, Wkt, D, D);
    transpose_f32_bf16<<<dim3(32, 32), tb, 0, stream>>>(wv, Wvt, D, D);
    transpose_f32_bf16<<<dim3(32, 32), tb, 0, stream>>>(wo, Wot, D, D);
    transpose_f32_bf16<<<dim3(128, 32), tb, 0, stream>>>(w1, W1t, D, DFF);
    transpose_f32_bf16<<<dim3(32, 128), tb, 0, stream>>>(w2, W2t, DFF, D);

    // Q, K, V = Xb @ W*t
    gemm_bt<128, 128, false><<<dim3(64, 8, 1), 256, 0, stream>>>(
        Xb, 0, 0, D, Wqt, 0, 0, D, D, 1, 1.f,
        nullptr, 0, nullptr, nullptr, 0, 0, 0,
        nullptr, Qb, 0, 0, D, 0);
    gemm_bt<128, 128, false><<<dim3(64, 8, 1), 256, 0, stream>>>(
        Xb, 0, 0, D, Wkt, 0, 0, D, D, 1, 1.f,
        nullptr, 0, nullptr, nullptr, 0, 0, 0,
        nullptr, Kb, 0, 0, D, 0);
    gemm_bt<128, 128, false><<<dim3(64, 8, 1), 256, 0, stream>>>(
        Xb, 0, 0, D, Wvt, 0, 0, D, D, 1, 1.f,
        nullptr, 0, nullptr, nullptr, 0, 0, 0,
        nullptr, Vb, 0, 0, D, 0);

    transpose_v<<<dim3(32, 2, 128), tb, 0, stream>>>(Vb, Vt);

    // scores = (Q @ K^T) / 8, masked -> attn region (raw, pre-softmax)
    gemm_bt<128, 128, false><<<dim3(8, 8, 128), 256, 0, stream>>>(
        Qb, (long)S * D, 64, D,
        Kb, (long)S * D, 64, D,
        DK, H, 0.125f,
        msk, S, nullptr, nullptr, 0, 0, 0,
        attn, nullptr, (long)H * S * S, (long)S * S, S, 0);

    softmax_rows<<<(int)((long)B * H * S / 4), 256, 0, stream>>>(attn);

    // ctx = attn @ V   (A is f32, converted during staging)
    gemm_bt<128, 64, true><<<dim3(8, 1, 128), 256, 0, stream>>>(
        attn, (long)H * S * S, (long)S * S, S,
        Vt, (long)H * DK * S, (long)DK * S, S,
        S, H, 1.f,
        nullptr, 0, nullptr, nullptr, 0, 0, 0,
        nullptr, Ctx, (long)S * D, 64, D, 0);

    // enc = ctx @ Wo + X   (write f32 + bf16)
    gemm_bt<128, 128, false><<<dim3(64, 8, 1), 256, 0, stream>>>(
        Ctx, 0, 0, D, Wot, 0, 0, D, D, 1, 1.f,
        nullptr, 0, nullptr,
        X, 0, 0, D,
        EncF, EncB, 0, 0, D, 0);

    // h = relu(enc @ W1 + b1)
    gemm_bt<128, 128, false><<<dim3(64, 32, 1), 256, 0, stream>>>(
        EncB, 0, 0, D, W1t, 0, 0, D, D, 1, 1.f,
        nullptr, 0, b1, nullptr, 0, 0, 0,
        nullptr, Hb, 0, 0, DFF, 1);

    // out = h @ W2 + b2 + enc
    gemm_bt<128, 128, false><<<dim3(64, 8, 1), 256, 0, stream>>>(
        Hb, 0, 0, DFF, W2t, 0, 0, DFF, DFF, 1, 1.f,
        nullptr, 0, b2,
        EncF, 0, 0, D,
        out, nullptr, 0, 0, D, 0);
}

// Round 2
// 685.631 us; speedup vs baseline: 1.6600x; 1.6600x over previous
//
#include <hip/hip_runtime.h>
#include <hip/hip_bf16.h>
#include <stdint.h>

// ---------------------------------------------------------------------------
// Types
// ---------------------------------------------------------------------------
typedef __bf16 bf16x8 __attribute__((ext_vector_type(8)));
typedef float  f32x4  __attribute__((ext_vector_type(4)));

typedef __attribute__((address_space(1))) void gvoid;
typedef __attribute__((address_space(3))) void lvoid;

__device__ __forceinline__ void async16(void* lds, const void* g) {
    // global -> LDS direct copy, 16B per lane; LDS dest = wave-uniform base + lane*16
    __builtin_amdgcn_global_load_lds((gvoid*)g, (lvoid*)lds, 16, 0, 0);
}

// ---------------------------------------------------------------------------
// Elementwise f32 -> bf16 convert
// ---------------------------------------------------------------------------
__global__ void cvt_f32_to_bf16(const float* __restrict__ in,
                                __hip_bfloat16* __restrict__ out, long n) {
    long i = ((long)blockIdx.x * blockDim.x + threadIdx.x) * 4;
    if (i < n) {
        float4 v = *(const float4*)(in + i);
        __hip_bfloat162* d = (__hip_bfloat162*)(out + i);
        d[0] = __float22bfloat162_rn(make_float2(v.x, v.y));
        d[1] = __float22bfloat162_rn(make_float2(v.z, v.w));
    }
}

// ---------------------------------------------------------------------------
// Transpose f32 [R][C] -> bf16 [C][R]   (weights; R,C multiples of 32)
// ---------------------------------------------------------------------------
__global__ void transpose_f32_bf16(const float* __restrict__ in,
                                   __hip_bfloat16* __restrict__ out,
                                   int R, int C) {
    __shared__ float t[32][33];
    int c0 = blockIdx.x * 32, r0 = blockIdx.y * 32;
    int tx = threadIdx.x, ty = threadIdx.y;
#pragma unroll
    for (int i = 0; i < 4; ++i) {
        int r = r0 + ty + i * 8;
        t[ty + i * 8][tx] = in[(long)r * C + c0 + tx];
    }
    __syncthreads();
#pragma unroll
    for (int i = 0; i < 4; ++i) {
        int c = c0 + ty + i * 8;
        out[(long)c * R + r0 + tx] = __float2bfloat16(t[tx][ty + i * 8]);
    }
}

// ---------------------------------------------------------------------------
// V [8192][1024] bf16  ->  Vt [128(bh)][64(d)][1024(s)] bf16
// ---------------------------------------------------------------------------
__global__ void transpose_v(const __hip_bfloat16* __restrict__ V,
                            __hip_bfloat16* __restrict__ Vt) {
    __shared__ __hip_bfloat16 t[32][33];
    int s0 = blockIdx.x * 32, d0 = blockIdx.y * 32, z = blockIdx.z;
    int b = z >> 4, h = z & 15;
    int tx = threadIdx.x, ty = threadIdx.y;
#pragma unroll
    for (int i = 0; i < 4; ++i) {
        int s = s0 + ty + i * 8;
        t[ty + i * 8][tx] = V[((long)b * 1024 + s) * 1024 + h * 64 + d0 + tx];
    }
    __syncthreads();
#pragma unroll
    for (int i = 0; i < 4; ++i) {
        int d = d0 + ty + i * 8;
        Vt[((long)z * 64 + d) * 1024 + s0 + tx] = t[tx][ty + i * 8];
    }
}

// ---------------------------------------------------------------------------
// Fused attention: per block = one (b,h) x 128 q-rows.
//   Phase 1: S = QK^T/8 + mask  -> running row max/sum (2-pass exact softmax)
//   Phase 2: recompute S, P = exp(S-m)/l -> write attn f32 (mandatory output),
//            P->bf16 into swizzled LDS, O += P @ V via MFMA.
// LDS tiles XOR-swizzled byte^((row&7)<<4); K/V staged via global_load_lds
// with pre-swizzled global source (linear LDS dest).
// ---------------------------------------------------------------------------
__global__ void __launch_bounds__(256, 2)
attn_fused(const __hip_bfloat16* __restrict__ Qb,
           const __hip_bfloat16* __restrict__ Kb,
           const __hip_bfloat16* __restrict__ Vt,
           const int* __restrict__ mask,
           float* __restrict__ attn,
           __hip_bfloat16* __restrict__ Ctx) {
    __shared__ __align__(16) __hip_bfloat16 sK[128 * 64];   // [s][dk] rows 128B
    __shared__ __align__(16) __hip_bfloat16 sV[64 * 128];   // [d][s]  rows 256B
    __shared__ __align__(16) __hip_bfloat16 sP[128 * 128];  // [q][s]  rows 256B
    __shared__ float smadd[1024];

    const int tid = threadIdx.x, lane = tid & 63, wave = tid >> 6;
    const int r16 = lane & 15, kg = lane >> 4;

    // dispatch swizzle: XCD k owns z = k*16..k*16+15 (K/V L2 locality)
    const int dd = blockIdx.x;
    const int wgt = (dd & 7) * 128 + (dd >> 3);
    const int xblk = wgt & 7, z = wgt >> 3;
    const int b = z >> 4, h = z & 15;
    const int row0 = xblk * 128;
    const int wrow = wave * 32;

    const __hip_bfloat16* Qz = Qb + ((long)b * 1024 + row0) * 1024 + h * 64;
    const __hip_bfloat16* Kz = Kb + (long)b * 1024 * 1024 + h * 64;
    const __hip_bfloat16* Vz = Vt + (long)z * 64 * 1024;
    float* attnZ = attn + (long)z * 1024 * 1024 + (long)row0 * 1024;

    for (int i = tid; i < 1024; i += 256)
        smadd[i] = mask[b * 1024 + i] ? 0.f : -1e9f;

    // Q fragments straight from global (read once)
    bf16x8 qa[2][2];
#pragma unroll
    for (int m = 0; m < 2; ++m)
#pragma unroll
        for (int kf = 0; kf < 2; ++kf)
            qa[m][kf] = *(const bf16x8*)(Qz + (long)(wrow + m * 16 + r16) * 1024 + kf * 32 + kg * 8);

    float mrow[2][4], lrow[2][4];
#pragma unroll
    for (int m = 0; m < 2; ++m)
#pragma unroll
        for (int i = 0; i < 4; ++i) { mrow[m][i] = -3e38f; lrow[m][i] = 0.f; }

    __syncthreads();

    const int ssw = (r16 & 7) << 4;  // read-side row swizzle (rows = mult16 + r16)

    // ---------------- phase 1: row stats ----------------
    for (int ct = 0; ct < 8; ++ct) {
#pragma unroll
        for (int j = 0; j < 4; ++j) {
            int c = wave * 4 + j;
            int s = c * 8 + (lane >> 3);
            int cb = (lane & 7) * 16;
            async16((char*)sK + c * 1024,
                    (const char*)(Kz + (long)(ct * 128 + s) * 1024) + (cb ^ ((s & 7) << 4)));
        }
        __syncthreads();

        f32x4 sacc[2][8];
#pragma unroll
        for (int m = 0; m < 2; ++m)
#pragma unroll
            for (int nf = 0; nf < 8; ++nf) sacc[m][nf] = f32x4{0.f, 0.f, 0.f, 0.f};

#pragma unroll
        for (int nf = 0; nf < 8; ++nf) {
            const char* kr = (const char*)sK + (nf * 16 + r16) * 128;
            bf16x8 bv0 = *(const bf16x8*)(kr + ((kg * 16) ^ ssw));
            bf16x8 bv1 = *(const bf16x8*)(kr + ((64 + kg * 16) ^ ssw));
#pragma unroll
            for (int m = 0; m < 2; ++m) {
                sacc[m][nf] = __builtin_amdgcn_mfma_f32_16x16x32_bf16(qa[m][0], bv0, sacc[m][nf], 0, 0, 0);
                sacc[m][nf] = __builtin_amdgcn_mfma_f32_16x16x32_bf16(qa[m][1], bv1, sacc[m][nf], 0, 0, 0);
            }
        }

        float madd[8];
#pragma unroll
        for (int nf = 0; nf < 8; ++nf) madd[nf] = smadd[ct * 128 + nf * 16 + r16];

#pragma unroll
        for (int m = 0; m < 2; ++m)
#pragma unroll
            for (int i = 0; i < 4; ++i) {
                float v[8];
                float tmax = -3e38f;
#pragma unroll
                for (int nf = 0; nf < 8; ++nf) {
                    float a = sacc[m][nf][i] * 0.125f + madd[nf];
                    v[nf] = a;
                    tmax = fmaxf(tmax, a);
                }
#pragma unroll
                for (int o = 1; o < 16; o <<= 1) tmax = fmaxf(tmax, __shfl_xor(tmax, o));
                float mnew = fmaxf(mrow[m][i], tmax);
                float corr = __expf(mrow[m][i] - mnew);
                float ts = 0.f;
#pragma unroll
                for (int nf = 0; nf < 8; ++nf) ts += __expf(v[nf] - mnew);
#pragma unroll
                for (int o = 1; o < 16; o <<= 1) ts += __shfl_xor(ts, o);
                lrow[m][i] = lrow[m][i] * corr + ts;
                mrow[m][i] = mnew;
            }
        __syncthreads();
    }

    float rinv[2][4];
#pragma unroll
    for (int m = 0; m < 2; ++m)
#pragma unroll
        for (int i = 0; i < 4; ++i) rinv[m][i] = 1.0f / lrow[m][i];

    f32x4 oacc[2][4];
#pragma unroll
    for (int m = 0; m < 2; ++m)
#pragma unroll
        for (int nf = 0; nf < 4; ++nf) oacc[m][nf] = f32x4{0.f, 0.f, 0.f, 0.f};

    // ---------------- phase 2: P write + PV ----------------
    for (int ct = 0; ct < 8; ++ct) {
#pragma unroll
        for (int j = 0; j < 4; ++j) {
            int c = wave * 4 + j;
            {  // K tile [128 s][64 dk]
                int s = c * 8 + (lane >> 3);
                int cb = (lane & 7) * 16;
                async16((char*)sK + c * 1024,
                        (const char*)(Kz + (long)(ct * 128 + s) * 1024) + (cb ^ ((s & 7) << 4)));
            }
            {  // V tile [64 d][128 s]
                int dv = c * 4 + (lane >> 4);
                int cb = (lane & 15) * 16;
                async16((char*)sV + c * 1024,
                        (const char*)(Vz + (long)dv * 1024 + ct * 128) + (cb ^ ((dv & 7) << 4)));
            }
        }
        __syncthreads();

        f32x4 sacc[2][8];
#pragma unroll
        for (int m = 0; m < 2; ++m)
#pragma unroll
            for (int nf = 0; nf < 8; ++nf) sacc[m][nf] = f32x4{0.f, 0.f, 0.f, 0.f};

#pragma unroll
        for (int nf = 0; nf < 8; ++nf) {
            const char* kr = (const char*)sK + (nf * 16 + r16) * 128;
            bf16x8 bv0 = *(const bf16x8*)(kr + ((kg * 16) ^ ssw));
            bf16x8 bv1 = *(const bf16x8*)(kr + ((64 + kg * 16) ^ ssw));
#pragma unroll
            for (int m = 0; m < 2; ++m) {
                sacc[m][nf] = __builtin_amdgcn_mfma_f32_16x16x32_bf16(qa[m][0], bv0, sacc[m][nf], 0, 0, 0);
                sacc[m][nf] = __builtin_amdgcn_mfma_f32_16x16x32_bf16(qa[m][1], bv1, sacc[m][nf], 0, 0, 0);
            }
        }

        float madd[8];
#pragma unroll
        for (int nf = 0; nf < 8; ++nf) madd[nf] = smadd[ct * 128 + nf * 16 + r16];

#pragma unroll
        for (int m = 0; m < 2; ++m)
#pragma unroll
            for (int nf = 0; nf < 8; ++nf) {
                int scol = nf * 16 + r16;
#pragma unroll
                for (int i = 0; i < 4; ++i) {
                    int q = wrow + m * 16 + kg * 4 + i;
                    float p = __expf(sacc[m][nf][i] * 0.125f + madd[nf] - mrow[m][i]) * rinv[m][i];
                    attnZ[(long)q * 1024 + ct * 128 + scol] = p;
                    *(__hip_bfloat16*)((char*)sP + q * 256 + ((scol * 2) ^ ((q & 7) << 4))) =
                        __float2bfloat16(p);
                }
            }

        // PV: O[q][d] += P[q][s] @ V^T[d][s]
#pragma unroll
        for (int ks = 0; ks < 4; ++ks) {
            bf16x8 pa[2], vv[4];
#pragma unroll
            for (int m = 0; m < 2; ++m)
                pa[m] = *(const bf16x8*)((const char*)sP + (wrow + m * 16 + r16) * 256 +
                                         ((ks * 64 + kg * 16) ^ ssw));
#pragma unroll
            for (int nf = 0; nf < 4; ++nf)
                vv[nf] = *(const bf16x8*)((const char*)sV + (nf * 16 + r16) * 256 +
                                          ((ks * 64 + kg * 16) ^ ssw));
#pragma unroll
            for (int m = 0; m < 2; ++m)
#pragma unroll
                for (int nf = 0; nf < 4; ++nf)
                    oacc[m][nf] = __builtin_amdgcn_mfma_f32_16x16x32_bf16(pa[m], vv[nf], oacc[m][nf], 0, 0, 0);
        }
        __syncthreads();
    }

    // epilogue: ctx bf16
#pragma unroll
    for (int m = 0; m < 2; ++m)
#pragma unroll
        for (int nf = 0; nf < 4; ++nf)
#pragma unroll
            for (int i = 0; i < 4; ++i) {
                int q = wrow + m * 16 + kg * 4 + i;
                Ctx[((long)b * 1024 + row0 + q) * 1024 + h * 64 + nf * 16 + r16] =
                    __float2bfloat16(oacc[m][nf][i]);
            }
}

// ---------------------------------------------------------------------------
// Batched GEMM:  C[z] = A[z] @ Bt[z]^T  (+ epilogue)
// ---------------------------------------------------------------------------
template <int BM, int BN>
__global__ void __launch_bounds__(256)
gemm_bt(const __hip_bfloat16* __restrict__ Ab_, long a_sb, long a_sh, int lda,
        const __hip_bfloat16* __restrict__ Bt, long b_sb, long b_sh, int ldb,
        int K, int H, float scale,
        const float* __restrict__ bias,
        const float* __restrict__ res, long r_sb, long r_sh, int ldres,
        float* __restrict__ Cf, __hip_bfloat16* __restrict__ Cb,
        long c_sb, long c_sh, int ldc, int relu) {
    constexpr int FM = BM / 32, FN = BN / 32;
    __shared__ __align__(16) __hip_bfloat16 sA[BM * 32];
    __shared__ __align__(16) __hip_bfloat16 sB[BN * 32];

    const int tid = threadIdx.x;
    const int lane = tid & 63, wave = tid >> 6;
    const int wr = wave >> 1, wc = wave & 1;
    const int r16 = lane & 15, kg = lane >> 4;
    const long zb = blockIdx.z / H, zh = blockIdx.z % H;
    const long row0 = (long)blockIdx.x * BM;
    const long col0 = (long)blockIdx.y * BN;

    const __hip_bfloat16* Ab = Ab_ + zb * a_sb + zh * a_sh;
    const __hip_bfloat16* Bb = Bt + zb * b_sb + zh * b_sh;

    f32x4 acc[FM][FN] = {};

    for (int kt = 0; kt < K; kt += 32) {
        {
            constexpr int CHA = BM / 16;  // 1KB chunks
            for (int c = wave; c < CHA; c += 4) {
                int e = c * 512 + lane * 8;
                int r = e >> 5, kk = e & 31;
                async16(&sA[c * 512], Ab + (row0 + r) * (long)lda + kt + kk);
            }
        }
        {
            constexpr int CHB = BN / 16;
            for (int c = wave; c < CHB; c += 4) {
                int e = c * 512 + lane * 8;
                int r = e >> 5, kk = e & 31;
                async16(&sB[c * 512], Bb + (col0 + r) * (long)ldb + kt + kk);
            }
        }
        __syncthreads();

        bf16x8 av[FM], bv[FN];
#pragma unroll
        for (int m = 0; m < FM; ++m)
            av[m] = *(const bf16x8*)&sA[(wr * (BM / 2) + m * 16 + r16) * 32 + kg * 8];
#pragma unroll
        for (int n = 0; n < FN; ++n)
            bv[n] = *(const bf16x8*)&sB[(wc * (BN / 2) + n * 16 + r16) * 32 + kg * 8];
#pragma unroll
        for (int m = 0; m < FM; ++m)
#pragma unroll
            for (int n = 0; n < FN; ++n)
                acc[m][n] = __builtin_amdgcn_mfma_f32_16x16x32_bf16(av[m], bv[n], acc[m][n], 0, 0, 0);
        __syncthreads();
    }

    const float* resb = res ? res + zb * r_sb + zh * r_sh : nullptr;
    float* cfb = Cf ? Cf + zb * c_sb + zh * c_sh : nullptr;
    __hip_bfloat16* cbb = Cb ? Cb + zb * c_sb + zh * c_sh : nullptr;

#pragma unroll
    for (int m = 0; m < FM; ++m) {
        const long rg0 = row0 + wr * (BM / 2) + m * 16 + kg * 4;
#pragma unroll
        for (int n = 0; n < FN; ++n) {
            const long cg = col0 + wc * (BN / 2) + n * 16 + r16;
#pragma unroll
            for (int i = 0; i < 4; ++i) {
                const long rg = rg0 + i;
                float v = acc[m][n][i] * scale;
                if (bias) v += bias[cg];
                if (relu) v = fmaxf(v, 0.f);
                if (resb) v += resb[rg * (long)ldres + cg];
                const long off = rg * (long)ldc + cg;
                if (cfb) cfb[off] = v;
                if (cbb) cbb[off] = __float2bfloat16(v);
            }
        }
    }
}

// ---------------------------------------------------------------------------
// Launch
// ---------------------------------------------------------------------------
extern "C" void kernel_launch(void* const* d_in, const int* in_sizes, int n_in,
                              void* d_out, int out_size, void* d_ws, size_t ws_size,
                              hipStream_t stream) {
    const int B = 8, S = 1024, D = 1024, H = 16, DFF = 4096;
    const long SD = (long)B * S * D;  // 8M

    const float* X  = (const float*)d_in[0];
    const int*  msk = (const int*)d_in[1];
    const float* wq = (const float*)d_in[3];
    const float* wk = (const float*)d_in[4];
    const float* wv = (const float*)d_in[5];
    const float* wo = (const float*)d_in[6];
    const float* w1 = (const float*)d_in[7];
    const float* b1 = (const float*)d_in[8];
    const float* w2 = (const float*)d_in[9];
    const float* b2 = (const float*)d_in[10];

    float* out  = (float*)d_out;
    float* attn = out + SD;  // [8][16][1024][1024]

    char* ws = (char*)d_ws;
    auto alloc = [&](size_t bytes) {
        char* p = ws;
        ws += (bytes + 255) & ~(size_t)255;
        return p;
    };
    __hip_bfloat16* Xb   = (__hip_bfloat16*)alloc(SD * 2);
    __hip_bfloat16* Qb   = (__hip_bfloat16*)alloc(SD * 2);
    __hip_bfloat16* Kb   = (__hip_bfloat16*)alloc(SD * 2);
    __hip_bfloat16* Vb   = (__hip_bfloat16*)alloc(SD * 2);
    __hip_bfloat16* Vt   = (__hip_bfloat16*)alloc(SD * 2);
    __hip_bfloat16* Ctx  = (__hip_bfloat16*)alloc(SD * 2);
    __hip_bfloat16* EncB = (__hip_bfloat16*)alloc(SD * 2);
    __hip_bfloat16* Hb   = (__hip_bfloat16*)alloc((long)B * S * DFF * 2);
    float*          EncF = (float*)alloc(SD * 4);
    __hip_bfloat16* Wqt  = (__hip_bfloat16*)alloc((long)D * D * 2);
    __hip_bfloat16* Wkt  = (__hip_bfloat16*)alloc((long)D * D * 2);
    __hip_bfloat16* Wvt  = (__hip_bfloat16*)alloc((long)D * D * 2);
    __hip_bfloat16* Wot  = (__hip_bfloat16*)alloc((long)D * D * 2);
    __hip_bfloat16* W1t  = (__hip_bfloat16*)alloc((long)D * DFF * 2);
    __hip_bfloat16* W2t  = (__hip_bfloat16*)alloc((long)D * DFF * 2);
    (void)ws_size; (void)in_sizes; (void)n_in; (void)out_size;

    dim3 tb(32, 8);
    cvt_f32_to_bf16<<<(int)(SD / 4 / 256), 256, 0, stream>>>(X, Xb, SD);
    transpose_f32_bf16<<<dim3(32, 32), tb, 0, stream>>>(wq, Wqt, D, D);
    transpose_f32_bf16<<<dim3(32, 32), tb, 0, stream>>>(wk, Wkt, D, D);
    transpose_f32_bf16<<<dim3(32, 32), tb, 0, stream>>>(wv, Wvt, D, D);
    transpose_f32_bf16<<<dim3(32, 32), tb, 0, stream>>>(wo, Wot, D, D);
    transpose_f32_bf16<<<dim3(128, 32), tb, 0, stream>>>(w1, W1t, D, DFF);
    transpose_f32_bf16<<<dim3(32, 128), tb, 0, stream>>>(w2, W2t, DFF, D);

    // Q, K, V = Xb @ W*t
    gemm_bt<128, 128><<<dim3(64, 8, 1), 256, 0, stream>>>(
        Xb, 0, 0, D, Wqt, 0, 0, D, D, 1, 1.f,
        nullptr, nullptr, 0, 0, 0,
        nullptr, Qb, 0, 0, D, 0);
    gemm_bt<128, 128><<<dim3(64, 8, 1), 256, 0, stream>>>(
        Xb, 0, 0, D, Wkt, 0, 0, D, D, 1, 1.f,
        nullptr, nullptr, 0, 0, 0,
        nullptr, Kb, 0, 0, D, 0);
    gemm_bt<128, 128><<<dim3(64, 8, 1), 256, 0, stream>>>(
        Xb, 0, 0, D, Wvt, 0, 0, D, D, 1, 1.f,
        nullptr, nullptr, 0, 0, 0,
        nullptr, Vb, 0, 0, D, 0);

    transpose_v<<<dim3(32, 2, 128), tb, 0, stream>>>(Vb, Vt);

    // fused attention: attn f32 + ctx bf16
    attn_fused<<<dim3(1024), 256, 0, stream>>>(Qb, Kb, Vt, msk, attn, Ctx);

    // enc = ctx @ Wo + X   (write f32 + bf16)
    gemm_bt<128, 128><<<dim3(64, 8, 1), 256, 0, stream>>>(
        Ctx, 0, 0, D, Wot, 0, 0, D, D, 1, 1.f,
        nullptr,
        X, 0, 0, D,
        EncF, EncB, 0, 0, D, 0);

    // h = relu(enc @ W1 + b1)
    gemm_bt<128, 128><<<dim3(64, 32, 1), 256, 0, stream>>>(
        EncB, 0, 0, D, W1t, 0, 0, D, D, 1, 1.f,
        b1, nullptr, 0, 0, 0,
        nullptr, Hb, 0, 0, DFF, 1);

    // out = h @ W2 + b2 + enc
    gemm_bt<128, 128><<<dim3(64, 8, 1), 256, 0, stream>>>(
        Hb, 0, 0, DFF, W2t, 0, 0, DFF, DFF, 1, 1.f,
        b2,
        EncF, 0, 0, D,
        out, nullptr, 0, 0, D, 0);
}

// Round 3
// 610.899 us; speedup vs baseline: 1.8631x; 1.1223x over previous
//
#include <hip/hip_runtime.h>
#include <hip/hip_bf16.h>
#include <stdint.h>

// ---------------------------------------------------------------------------
// Types
// ---------------------------------------------------------------------------
typedef __bf16 bf16x8 __attribute__((ext_vector_type(8)));
typedef float  f32x4  __attribute__((ext_vector_type(4)));

typedef __attribute__((address_space(1))) void gvoid;
typedef __attribute__((address_space(3))) void lvoid;

__device__ __forceinline__ void async16(void* lds, const void* g) {
    __builtin_amdgcn_global_load_lds((gvoid*)g, (lvoid*)lds, 16, 0, 0);
}

// ---------------------------------------------------------------------------
// Elementwise f32 -> bf16 convert
// ---------------------------------------------------------------------------
__global__ void cvt_f32_to_bf16(const float* __restrict__ in,
                                __hip_bfloat16* __restrict__ out, long n) {
    long i = ((long)blockIdx.x * blockDim.x + threadIdx.x) * 4;
    if (i < n) {
        float4 v = *(const float4*)(in + i);
        __hip_bfloat162* d = (__hip_bfloat162*)(out + i);
        d[0] = __float22bfloat162_rn(make_float2(v.x, v.y));
        d[1] = __float22bfloat162_rn(make_float2(v.z, v.w));
    }
}

// ---------------------------------------------------------------------------
// Transpose f32 [R][C] -> bf16 [C][R]
// ---------------------------------------------------------------------------
__global__ void transpose_f32_bf16(const float* __restrict__ in,
                                   __hip_bfloat16* __restrict__ out,
                                   int R, int C) {
    __shared__ float t[32][33];
    int c0 = blockIdx.x * 32, r0 = blockIdx.y * 32;
    int tx = threadIdx.x, ty = threadIdx.y;
#pragma unroll
    for (int i = 0; i < 4; ++i) {
        int r = r0 + ty + i * 8;
        t[ty + i * 8][tx] = in[(long)r * C + c0 + tx];
    }
    __syncthreads();
#pragma unroll
    for (int i = 0; i < 4; ++i) {
        int c = c0 + ty + i * 8;
        out[(long)c * R + r0 + tx] = __float2bfloat16(t[tx][ty + i * 8]);
    }
}

// ---------------------------------------------------------------------------
// V (cols 2048..3071 of QKVb [8192][3072]) -> Vt [128(bh)][64(d)][1024(s)]
// ---------------------------------------------------------------------------
__global__ void transpose_v(const __hip_bfloat16* __restrict__ QKV,
                            __hip_bfloat16* __restrict__ Vt) {
    __shared__ __hip_bfloat16 t[32][33];
    int s0 = blockIdx.x * 32, d0 = blockIdx.y * 32, z = blockIdx.z;
    int b = z >> 4, h = z & 15;
    int tx = threadIdx.x, ty = threadIdx.y;
#pragma unroll
    for (int i = 0; i < 4; ++i) {
        int s = s0 + ty + i * 8;
        t[ty + i * 8][tx] = QKV[((long)b * 1024 + s) * 3072 + 2048 + h * 64 + d0 + tx];
    }
    __syncthreads();
#pragma unroll
    for (int i = 0; i < 4; ++i) {
        int d = d0 + ty + i * 8;
        Vt[((long)z * 64 + d) * 1024 + s0 + tx] = t[tx][ty + i * 8];
    }
}

// ---------------------------------------------------------------------------
// Fused attention (Q,K from QKVb stride 3072; V from Vt).
// ---------------------------------------------------------------------------
__global__ void __launch_bounds__(256, 2)
attn_fused(const __hip_bfloat16* __restrict__ QKV,
           const __hip_bfloat16* __restrict__ Vt,
           const int* __restrict__ mask,
           float* __restrict__ attn,
           __hip_bfloat16* __restrict__ Ctx) {
    __shared__ __align__(16) __hip_bfloat16 sK[128 * 64];
    __shared__ __align__(16) __hip_bfloat16 sV[64 * 128];
    __shared__ __align__(16) __hip_bfloat16 sP[128 * 128];
    __shared__ float smadd[1024];

    const int tid = threadIdx.x, lane = tid & 63, wave = tid >> 6;
    const int r16 = lane & 15, kg = lane >> 4;

    const int dd = blockIdx.x;
    const int wgt = (dd & 7) * 128 + (dd >> 3);
    const int xblk = wgt & 7, z = wgt >> 3;
    const int b = z >> 4, h = z & 15;
    const int row0 = xblk * 128;
    const int wrow = wave * 32;

    const __hip_bfloat16* Qz = QKV + ((long)b * 1024 + row0) * 3072 + h * 64;
    const __hip_bfloat16* Kz = QKV + (long)b * 1024 * 3072 + 1024 + h * 64;
    const __hip_bfloat16* Vz = Vt + (long)z * 64 * 1024;
    float* attnZ = attn + (long)z * 1024 * 1024 + (long)row0 * 1024;

    for (int i = tid; i < 1024; i += 256)
        smadd[i] = mask[b * 1024 + i] ? 0.f : -1e9f;

    bf16x8 qa[2][2];
#pragma unroll
    for (int m = 0; m < 2; ++m)
#pragma unroll
        for (int kf = 0; kf < 2; ++kf)
            qa[m][kf] = *(const bf16x8*)(Qz + (long)(wrow + m * 16 + r16) * 3072 + kf * 32 + kg * 8);

    float mrow[2][4], lrow[2][4];
#pragma unroll
    for (int m = 0; m < 2; ++m)
#pragma unroll
        for (int i = 0; i < 4; ++i) { mrow[m][i] = -3e38f; lrow[m][i] = 0.f; }

    __syncthreads();

    const int ssw = (r16 & 7) << 4;

    // ---------------- phase 1: row stats ----------------
    for (int ct = 0; ct < 8; ++ct) {
#pragma unroll
        for (int j = 0; j < 4; ++j) {
            int c = wave * 4 + j;
            int s = c * 8 + (lane >> 3);
            int cb = (lane & 7) * 16;
            async16((char*)sK + c * 1024,
                    (const char*)(Kz + (long)(ct * 128 + s) * 3072) + (cb ^ ((s & 7) << 4)));
        }
        __syncthreads();

        f32x4 sacc[2][8];
#pragma unroll
        for (int m = 0; m < 2; ++m)
#pragma unroll
            for (int nf = 0; nf < 8; ++nf) sacc[m][nf] = f32x4{0.f, 0.f, 0.f, 0.f};

#pragma unroll
        for (int nf = 0; nf < 8; ++nf) {
            const char* kr = (const char*)sK + (nf * 16 + r16) * 128;
            bf16x8 bv0 = *(const bf16x8*)(kr + ((kg * 16) ^ ssw));
            bf16x8 bv1 = *(const bf16x8*)(kr + ((64 + kg * 16) ^ ssw));
#pragma unroll
            for (int m = 0; m < 2; ++m) {
                sacc[m][nf] = __builtin_amdgcn_mfma_f32_16x16x32_bf16(qa[m][0], bv0, sacc[m][nf], 0, 0, 0);
                sacc[m][nf] = __builtin_amdgcn_mfma_f32_16x16x32_bf16(qa[m][1], bv1, sacc[m][nf], 0, 0, 0);
            }
        }

        float madd[8];
#pragma unroll
        for (int nf = 0; nf < 8; ++nf) madd[nf] = smadd[ct * 128 + nf * 16 + r16];

#pragma unroll
        for (int m = 0; m < 2; ++m)
#pragma unroll
            for (int i = 0; i < 4; ++i) {
                float v[8];
                float tmax = -3e38f;
#pragma unroll
                for (int nf = 0; nf < 8; ++nf) {
                    float a = sacc[m][nf][i] * 0.125f + madd[nf];
                    v[nf] = a;
                    tmax = fmaxf(tmax, a);
                }
#pragma unroll
                for (int o = 1; o < 16; o <<= 1) tmax = fmaxf(tmax, __shfl_xor(tmax, o));
                float mnew = fmaxf(mrow[m][i], tmax);
                float corr = __expf(mrow[m][i] - mnew);
                float ts = 0.f;
#pragma unroll
                for (int nf = 0; nf < 8; ++nf) ts += __expf(v[nf] - mnew);
#pragma unroll
                for (int o = 1; o < 16; o <<= 1) ts += __shfl_xor(ts, o);
                lrow[m][i] = lrow[m][i] * corr + ts;
                mrow[m][i] = mnew;
            }
        __syncthreads();
    }

    float rinv[2][4];
#pragma unroll
    for (int m = 0; m < 2; ++m)
#pragma unroll
        for (int i = 0; i < 4; ++i) rinv[m][i] = 1.0f / lrow[m][i];

    f32x4 oacc[2][4];
#pragma unroll
    for (int m = 0; m < 2; ++m)
#pragma unroll
        for (int nf = 0; nf < 4; ++nf) oacc[m][nf] = f32x4{0.f, 0.f, 0.f, 0.f};

    // ---------------- phase 2: P write + PV ----------------
    for (int ct = 0; ct < 8; ++ct) {
#pragma unroll
        for (int j = 0; j < 4; ++j) {
            int c = wave * 4 + j;
            {
                int s = c * 8 + (lane >> 3);
                int cb = (lane & 7) * 16;
                async16((char*)sK + c * 1024,
                        (const char*)(Kz + (long)(ct * 128 + s) * 3072) + (cb ^ ((s & 7) << 4)));
            }
            {
                int dv = c * 4 + (lane >> 4);
                int cb = (lane & 15) * 16;
                async16((char*)sV + c * 1024,
                        (const char*)(Vz + (long)dv * 1024 + ct * 128) + (cb ^ ((dv & 7) << 4)));
            }
        }
        __syncthreads();

        f32x4 sacc[2][8];
#pragma unroll
        for (int m = 0; m < 2; ++m)
#pragma unroll
            for (int nf = 0; nf < 8; ++nf) sacc[m][nf] = f32x4{0.f, 0.f, 0.f, 0.f};

#pragma unroll
        for (int nf = 0; nf < 8; ++nf) {
            const char* kr = (const char*)sK + (nf * 16 + r16) * 128;
            bf16x8 bv0 = *(const bf16x8*)(kr + ((kg * 16) ^ ssw));
            bf16x8 bv1 = *(const bf16x8*)(kr + ((64 + kg * 16) ^ ssw));
#pragma unroll
            for (int m = 0; m < 2; ++m) {
                sacc[m][nf] = __builtin_amdgcn_mfma_f32_16x16x32_bf16(qa[m][0], bv0, sacc[m][nf], 0, 0, 0);
                sacc[m][nf] = __builtin_amdgcn_mfma_f32_16x16x32_bf16(qa[m][1], bv1, sacc[m][nf], 0, 0, 0);
            }
        }

        float madd[8];
#pragma unroll
        for (int nf = 0; nf < 8; ++nf) madd[nf] = smadd[ct * 128 + nf * 16 + r16];

#pragma unroll
        for (int m = 0; m < 2; ++m)
#pragma unroll
            for (int nf = 0; nf < 8; ++nf) {
                int scol = nf * 16 + r16;
#pragma unroll
                for (int i = 0; i < 4; ++i) {
                    int q = wrow + m * 16 + kg * 4 + i;
                    float p = __expf(sacc[m][nf][i] * 0.125f + madd[nf] - mrow[m][i]) * rinv[m][i];
                    attnZ[(long)q * 1024 + ct * 128 + scol] = p;
                    *(__hip_bfloat16*)((char*)sP + q * 256 + ((scol * 2) ^ ((q & 7) << 4))) =
                        __float2bfloat16(p);
                }
            }

#pragma unroll
        for (int ks = 0; ks < 4; ++ks) {
            bf16x8 pa[2], vv[4];
#pragma unroll
            for (int m = 0; m < 2; ++m)
                pa[m] = *(const bf16x8*)((const char*)sP + (wrow + m * 16 + r16) * 256 +
                                         ((ks * 64 + kg * 16) ^ ssw));
#pragma unroll
            for (int nf = 0; nf < 4; ++nf)
                vv[nf] = *(const bf16x8*)((const char*)sV + (nf * 16 + r16) * 256 +
                                          ((ks * 64 + kg * 16) ^ ssw));
#pragma unroll
            for (int m = 0; m < 2; ++m)
#pragma unroll
                for (int nf = 0; nf < 4; ++nf)
                    oacc[m][nf] = __builtin_amdgcn_mfma_f32_16x16x32_bf16(pa[m], vv[nf], oacc[m][nf], 0, 0, 0);
        }
        __syncthreads();
    }

#pragma unroll
    for (int m = 0; m < 2; ++m)
#pragma unroll
        for (int nf = 0; nf < 4; ++nf)
#pragma unroll
            for (int i = 0; i < 4; ++i) {
                int q = wrow + m * 16 + kg * 4 + i;
                Ctx[((long)b * 1024 + row0 + q) * 1024 + h * 64 + nf * 16 + r16] =
                    __float2bfloat16(oacc[m][nf][i]);
            }
}

// ---------------------------------------------------------------------------
// 128x128 GEMM (m97 structure) — used for N=1024 shapes (Wo, FFN2)
// ---------------------------------------------------------------------------
template <int BM, int BN>
__global__ void __launch_bounds__(256)
gemm_bt(const __hip_bfloat16* __restrict__ Ab_, int lda,
        const __hip_bfloat16* __restrict__ Bt, int ldb,
        int K, float scale,
        const float* __restrict__ bias,
        const float* __restrict__ res, int ldres,
        float* __restrict__ Cf, __hip_bfloat16* __restrict__ Cb,
        int ldc, int relu) {
    constexpr int FM = BM / 32, FN = BN / 32;
    __shared__ __align__(16) __hip_bfloat16 sA[BM * 32];
    __shared__ __align__(16) __hip_bfloat16 sB[BN * 32];

    const int tid = threadIdx.x;
    const int lane = tid & 63, wave = tid >> 6;
    const int wr = wave >> 1, wc = wave & 1;
    const int r16 = lane & 15, kg = lane >> 4;
    const long row0 = (long)blockIdx.x * BM;
    const long col0 = (long)blockIdx.y * BN;

    const __hip_bfloat16* Ab = Ab_;
    const __hip_bfloat16* Bb = Bt;

    f32x4 acc[FM][FN] = {};

    for (int kt = 0; kt < K; kt += 32) {
        {
            constexpr int CHA = BM / 16;
            for (int c = wave; c < CHA; c += 4) {
                int e = c * 512 + lane * 8;
                int r = e >> 5, kk = e & 31;
                async16(&sA[c * 512], Ab + (row0 + r) * (long)lda + kt + kk);
            }
        }
        {
            constexpr int CHB = BN / 16;
            for (int c = wave; c < CHB; c += 4) {
                int e = c * 512 + lane * 8;
                int r = e >> 5, kk = e & 31;
                async16(&sB[c * 512], Bb + (col0 + r) * (long)ldb + kt + kk);
            }
        }
        __syncthreads();

        bf16x8 av[FM], bv[FN];
#pragma unroll
        for (int m = 0; m < FM; ++m)
            av[m] = *(const bf16x8*)&sA[(wr * (BM / 2) + m * 16 + r16) * 32 + kg * 8];
#pragma unroll
        for (int n = 0; n < FN; ++n)
            bv[n] = *(const bf16x8*)&sB[(wc * (BN / 2) + n * 16 + r16) * 32 + kg * 8];
#pragma unroll
        for (int m = 0; m < FM; ++m)
#pragma unroll
            for (int n = 0; n < FN; ++n)
                acc[m][n] = __builtin_amdgcn_mfma_f32_16x16x32_bf16(av[m], bv[n], acc[m][n], 0, 0, 0);
        __syncthreads();
    }

#pragma unroll
    for (int m = 0; m < FM; ++m) {
        const long rg0 = row0 + wr * (BM / 2) + m * 16 + kg * 4;
#pragma unroll
        for (int n = 0; n < FN; ++n) {
            const long cg = col0 + wc * (BN / 2) + n * 16 + r16;
#pragma unroll
            for (int i = 0; i < 4; ++i) {
                const long rg = rg0 + i;
                float v = acc[m][n][i] * scale;
                if (bias) v += bias[cg];
                if (relu) v = fmaxf(v, 0.f);
                if (res) v += res[rg * (long)ldres + cg];
                const long off = rg * (long)ldc + cg;
                if (Cf) Cf[off] = v;
                if (Cb) Cb[off] = __float2bfloat16(v);
            }
        }
    }
}

// ---------------------------------------------------------------------------
// 256x256 8-phase GEMM (T2+T3+T4+T5).  C = A @ Bt^T (+bias, relu) -> bf16.
// 512 thr = 8 waves (2Mx4N); BK=64; 2 LDS buffers (128KB); per-phase one
// half-tile staged into retired space; vmcnt(4) at phases 4/8 only.
// LDS unit order A:[pm][wr][64r][64c-swz], B:[pn][wc][32r][64c-swz];
// swizzle: byte_in_row ^= ((row&7)<<4), applied via pre-swizzled global src.
// ---------------------------------------------------------------------------
#define RDA(BUF, PM, ML, KS) \
    (*(const bf16x8*)(aRd + (BUF)*32768 + (PM)*16384 + (ML)*2048 + ((((KS)*64) + kg*16) ^ sw)))
#define RDB(BUF, PN, NL, KS) \
    (*(const bf16x8*)(bRd + (BUF)*32768 + (PN)*16384 + (NL)*2048 + ((((KS)*64) + kg*16) ^ sw)))
#define LOAD_A(BUF, PM)                          \
    _Pragma("unroll") for (int ml = 0; ml < 4; ++ml) \
    _Pragma("unroll") for (int ks = 0; ks < 2; ++ks) \
        a[ml][ks] = RDA(BUF, PM, ml, ks)
#define LOAD_B(DST, BUF, PN)                     \
    _Pragma("unroll") for (int nl = 0; nl < 2; ++nl) \
    _Pragma("unroll") for (int ks = 0; ks < 2; ++ks) \
        DST[nl][ks] = RDB(BUF, PN, nl, ks)
#define MFMA16(PM, PN, BB)                                                   \
    __builtin_amdgcn_s_setprio(1);                                           \
    _Pragma("unroll") for (int ks = 0; ks < 2; ++ks)                         \
    _Pragma("unroll") for (int ml = 0; ml < 4; ++ml)                         \
    _Pragma("unroll") for (int nl = 0; nl < 2; ++nl)                         \
        acc[(PM)*4 + ml][(PN)*2 + nl] = __builtin_amdgcn_mfma_f32_16x16x32_bf16( \
            a[ml][ks], BB[nl][ks], acc[(PM)*4 + ml][(PN)*2 + nl], 0, 0, 0);  \
    __builtin_amdgcn_s_setprio(0)
#define BAR asm volatile("s_barrier" ::: "memory")

__global__ void __launch_bounds__(512, 2)
gemm256(const __hip_bfloat16* __restrict__ A, int lda,
        const __hip_bfloat16* __restrict__ Bt, int ldb,
        int K, int Mtiles,
        const float* __restrict__ bias, int relu,
        __hip_bfloat16* __restrict__ C, int ldc) {
    __shared__ __align__(16) char lds[131072];
    const int NT = K >> 6;
    const int tid = threadIdx.x, lane = tid & 63, wave = tid >> 6;
    const int r16 = lane & 15, kg = lane >> 4;
    const int wr = wave >> 2, wc = wave & 3;
    const int sw = (r16 & 7) << 4;

    // bijective XCD swizzle (m204)
    const int nwg = gridDim.x;
    const int q8 = nwg >> 3, r8 = nwg & 7;
    const int xcd = blockIdx.x & 7, rest = blockIdx.x >> 3;
    const int wg = (xcd < r8 ? xcd * (q8 + 1) : r8 * (q8 + 1) + (xcd - r8) * q8) + rest;
    const int tm = wg % Mtiles, tn = wg / Mtiles;
    const long row0 = (long)tm * 256, col0 = (long)tn * 256;

    // staging source pointers (pre-swizzled)
    const int idx = tid >> 3;                          // 0..63
    const int slotp = ((tid & 7) ^ (idx & 7)) * 8;     // source col (elems)
    const __hip_bfloat16* aSrc[4];
    const __hip_bfloat16* bSrc[4];
#pragma unroll
    for (int j = 0; j < 4; ++j) {
        long ar = row0 + (j & 1) * 128 + (j >> 1) * 64 + idx;
        aSrc[j] = A + ar * lda + slotp;
        long br = col0 + ((j & 1) * 2 + (tid >> 8)) * 64 + (j >> 1) * 32 + (idx & 31);
        bSrc[j] = Bt + br * ldb + slotp;
    }

    char* ldsA = lds;
    char* ldsB = lds + 65536;
    const int stDst = wave * 1024;
    auto stA = [&](int v, int j) {
        async16(ldsA + ((v & 1) << 15) + (j << 13) + stDst, aSrc[j] + (v << 6));
    };
    auto stB = [&](int v, int j) {
        async16(ldsB + ((v & 1) << 15) + (j << 13) + stDst, bSrc[j] + (v << 6));
    };

    // prologue: tile0 complete + A0,B0 of tile1
    stA(0, 0); stA(0, 1); stB(0, 0); stB(0, 1);
    stA(0, 2); stA(0, 3); stB(0, 2); stB(0, 3);
    stA(1, 0); stA(1, 1); stB(1, 0); stB(1, 1);
    asm volatile("s_waitcnt vmcnt(4)" ::: "memory");
    BAR;

    f32x4 acc[8][4] = {};
    const char* aRd = ldsA + wr * 8192 + r16 * 128;
    const char* bRd = ldsB + wc * 4096 + r16 * 128;

    for (int u = 0; u < NT; u += 2) {
        const bool more = (u + 2) < NT;
        bf16x8 a[4][2], b0[2][2], b1[2][2];

        // ph1: quad(0,0) tile u (buf0); stage A1(u+1)
        LOAD_A(0, 0);
        LOAD_B(b0, 0, 0);
        stA(u + 1, 2); stA(u + 1, 3);
        MFMA16(0, 0, b0);
        BAR;
        // ph2: quad(0,1); stage B1(u+1)
        LOAD_B(b1, 0, 1);
        stB(u + 1, 2); stB(u + 1, 3);
        MFMA16(0, 1, b1);
        BAR;
        // ph3: quad(1,0); stage A0(u+2)
        LOAD_A(0, 1);
        if (more) { stA(u + 2, 0); stA(u + 2, 1); }
        MFMA16(1, 0, b0);
        BAR;
        // ph4: quad(1,1); stage B0(u+2); counted wait
        if (more) {
            stB(u + 2, 0); stB(u + 2, 1);
            asm volatile("s_waitcnt vmcnt(4)" ::: "memory");
        } else {
            asm volatile("s_waitcnt vmcnt(0)" ::: "memory");
        }
        MFMA16(1, 1, b1);
        BAR;
        // ph5: quad(0,0) tile u+1 (buf1); stage A1(u+2)
        LOAD_A(1, 0);
        LOAD_B(b0, 1, 0);
        if (more) { stA(u + 2, 2); stA(u + 2, 3); }
        MFMA16(0, 0, b0);
        BAR;
        // ph6: quad(0,1); stage B1(u+2)
        LOAD_B(b1, 1, 1);
        if (more) { stB(u + 2, 2); stB(u + 2, 3); }
        MFMA16(0, 1, b1);
        BAR;
        // ph7: quad(1,0); stage A0(u+3)
        LOAD_A(1, 1);
        if (more) { stA(u + 3, 0); stA(u + 3, 1); }
        MFMA16(1, 0, b0);
        BAR;
        // ph8: quad(1,1); stage B0(u+3); counted wait
        if (more) {
            stB(u + 3, 0); stB(u + 3, 1);
            asm volatile("s_waitcnt vmcnt(4)" ::: "memory");
        }
        MFMA16(1, 1, b1);
        BAR;
    }

    // epilogue
    const long crow = row0 + wr * 128, ccol = col0 + wc * 64;
#pragma unroll
    for (int mf = 0; mf < 8; ++mf)
#pragma unroll
        for (int nf = 0; nf < 4; ++nf) {
            const long col = ccol + nf * 16 + r16;
            const float bs = bias ? bias[col] : 0.f;
#pragma unroll
            for (int i = 0; i < 4; ++i) {
                const long row = crow + mf * 16 + kg * 4 + i;
                float v = acc[mf][nf][i] + bs;
                if (relu) v = fmaxf(v, 0.f);
                C[row * (long)ldc + col] = __float2bfloat16(v);
            }
        }
}

// ---------------------------------------------------------------------------
// Launch
// ---------------------------------------------------------------------------
extern "C" void kernel_launch(void* const* d_in, const int* in_sizes, int n_in,
                              void* d_out, int out_size, void* d_ws, size_t ws_size,
                              hipStream_t stream) {
    const int B = 8, S = 1024, D = 1024, DFF = 4096;
    const long SD = (long)B * S * D;  // 8M

    const float* X  = (const float*)d_in[0];
    const int*  msk = (const int*)d_in[1];
    const float* wq = (const float*)d_in[3];
    const float* wk = (const float*)d_in[4];
    const float* wv = (const float*)d_in[5];
    const float* wo = (const float*)d_in[6];
    const float* w1 = (const float*)d_in[7];
    const float* b1 = (const float*)d_in[8];
    const float* w2 = (const float*)d_in[9];
    const float* b2 = (const float*)d_in[10];

    float* out  = (float*)d_out;
    float* attn = out + SD;

    char* ws = (char*)d_ws;
    auto alloc = [&](size_t bytes) {
        char* p = ws;
        ws += (bytes + 255) & ~(size_t)255;
        return p;
    };
    __hip_bfloat16* Xb   = (__hip_bfloat16*)alloc(SD * 2);
    __hip_bfloat16* QKVb = (__hip_bfloat16*)alloc(SD * 3 * 2);  // [8192][3072]
    __hip_bfloat16* Vt   = (__hip_bfloat16*)alloc(SD * 2);
    __hip_bfloat16* Ctx  = (__hip_bfloat16*)alloc(SD * 2);
    __hip_bfloat16* EncB = (__hip_bfloat16*)alloc(SD * 2);
    __hip_bfloat16* Hb   = (__hip_bfloat16*)alloc((long)B * S * DFF * 2);
    float*          EncF = (float*)alloc(SD * 4);
    __hip_bfloat16* Wcat = (__hip_bfloat16*)alloc((long)3 * D * D * 2);  // [3072][1024]
    __hip_bfloat16* Wot  = (__hip_bfloat16*)alloc((long)D * D * 2);
    __hip_bfloat16* W1t  = (__hip_bfloat16*)alloc((long)D * DFF * 2);
    __hip_bfloat16* W2t  = (__hip_bfloat16*)alloc((long)D * DFF * 2);
    (void)ws_size; (void)in_sizes; (void)n_in; (void)out_size;

    dim3 tb(32, 8);
    cvt_f32_to_bf16<<<(int)(SD / 4 / 256), 256, 0, stream>>>(X, Xb, SD);
    transpose_f32_bf16<<<dim3(32, 32), tb, 0, stream>>>(wq, Wcat, D, D);
    transpose_f32_bf16<<<dim3(32, 32), tb, 0, stream>>>(wk, Wcat + (long)D * D, D, D);
    transpose_f32_bf16<<<dim3(32, 32), tb, 0, stream>>>(wv, Wcat + (long)2 * D * D, D, D);
    transpose_f32_bf16<<<dim3(32, 32), tb, 0, stream>>>(wo, Wot, D, D);
    transpose_f32_bf16<<<dim3(128, 32), tb, 0, stream>>>(w1, W1t, D, DFF);
    transpose_f32_bf16<<<dim3(32, 128), tb, 0, stream>>>(w2, W2t, DFF, D);

    // QKV = Xb @ Wcat^T   [8192][3072]   (256^2 8-phase)
    gemm256<<<dim3(32 * 12), 512, 0, stream>>>(
        Xb, D, Wcat, D, D, 32, nullptr, 0, QKVb, 3 * D);

    transpose_v<<<dim3(32, 2, 128), tb, 0, stream>>>(QKVb, Vt);

    // fused attention
    attn_fused<<<dim3(1024), 256, 0, stream>>>(QKVb, Vt, msk, attn, Ctx);

    // enc = ctx @ Wo + X  (f32 + bf16)
    gemm_bt<128, 128><<<dim3(64, 8), 256, 0, stream>>>(
        Ctx, D, Wot, D, D, 1.f,
        nullptr, X, D,
        EncF, EncB, D, 0);

    // h = relu(enc @ W1 + b1)   (256^2 8-phase)
    gemm256<<<dim3(32 * 16), 512, 0, stream>>>(
        EncB, D, W1t, D, D, 32, b1, 1, Hb, DFF);

    // out = h @ W2 + b2 + enc
    gemm_bt<128, 128><<<dim3(64, 8), 256, 0, stream>>>(
        Hb, DFF, W2t, DFF, DFF, 1.f,
        b2, EncF, D,
        out, nullptr, D, 0);
}